// Round 3
// baseline (219.700 us; speedup 1.0000x reference)
//
#include <hip/hip_runtime.h>
#include <hip/hip_cooperative_groups.h>

namespace cg = cooperative_groups;

#define SIZE_IN   8192
#define SIZE_OUT  2048
#define CH        16                 // i's per split
#define NSPLIT    (SIZE_IN / CH)     // 512 splits
#define JT        2                  // j tiles per split
#define JTILE     (SIZE_OUT / JT)    // 1024 floats
#define BLOCK     256
#define GRID      (NSPLIT * JT)      // 1024 blocks = 16 waves/CU (co-resident)

// Fused: phase 1 computes split-K partials into ws; grid-wide sync; phase 2
// has the first 512 blocks each reduce one float4 output column (+bias).
__global__ __launch_bounds__(BLOCK, 4) void ill_fused(
    const float* __restrict__ x,
    const int*   __restrict__ idx,
    const float* __restrict__ w,
    const float* __restrict__ bias,
    float*       __restrict__ out,
    float*       __restrict__ ws)
{
    const int tid = threadIdx.x;
    const int bid = blockIdx.x;

    // ---- phase 1: partial sums over one i-chunk, one j half ----
    {
        const int jt = bid & (JT - 1);
        const int ic = bid >> 1;
        const int j  = jt * JTILE + tid * 4;
        const int i0 = ic * CH;

        float4 acc = make_float4(0.f, 0.f, 0.f, 0.f);
        #pragma unroll
        for (int k = 0; k < CH; ++k) {
            const int    i  = i0 + k;              // wave-uniform -> s_load path
            const float  xv = x[i];
            const size_t q  = (size_t)idx[i];
            const float4 wv = *reinterpret_cast<const float4*>(
                w + ((q << 13) + (size_t)i) * (size_t)SIZE_OUT + j);
            acc.x += xv * wv.x;
            acc.y += xv * wv.y;
            acc.z += xv * wv.z;
            acc.w += xv * wv.w;
        }
        *reinterpret_cast<float4*>(ws + (size_t)ic * SIZE_OUT + j) = acc;
    }

    __threadfence();          // device-scope: publish ws across XCDs
    cg::this_grid().sync();

    // ---- phase 2: one block per float4 column ----
    if (bid < SIZE_OUT / 4) {
        const float4* ws4 = reinterpret_cast<const float4*>(ws);
        float4 acc = make_float4(0.f, 0.f, 0.f, 0.f);
        #pragma unroll
        for (int s = tid; s < NSPLIT; s += BLOCK) {   // 2 loads/thread, fixed order
            const float4 v = ws4[(size_t)s * (SIZE_OUT / 4) + bid];
            acc.x += v.x; acc.y += v.y; acc.z += v.z; acc.w += v.w;
        }
        #pragma unroll
        for (int off = 32; off > 0; off >>= 1) {
            acc.x += __shfl_down(acc.x, off, 64);
            acc.y += __shfl_down(acc.y, off, 64);
            acc.z += __shfl_down(acc.z, off, 64);
            acc.w += __shfl_down(acc.w, off, 64);
        }
        __shared__ float4 sred[BLOCK / 64];
        const int lane = tid & 63;
        const int wvid = tid >> 6;
        if (lane == 0) sred[wvid] = acc;
        __syncthreads();
        if (tid == 0) {
            float4 a = sred[0];
            #pragma unroll
            for (int u = 1; u < BLOCK / 64; ++u) {
                a.x += sred[u].x; a.y += sred[u].y;
                a.z += sred[u].z; a.w += sred[u].w;
            }
            const float4 b = reinterpret_cast<const float4*>(bias)[bid];
            reinterpret_cast<float4*>(out)[bid] =
                make_float4(a.x + b.x, a.y + b.y, a.z + b.z, a.w + b.w);
        }
    }
}

extern "C" void kernel_launch(void* const* d_in, const int* in_sizes, int n_in,
                              void* d_out, int out_size, void* d_ws, size_t ws_size,
                              hipStream_t stream) {
    const float* x    = (const float*)d_in[0];
    const int*   idx  = (const int*)d_in[1];
    const float* w    = (const float*)d_in[2];
    const float* bias = (const float*)d_in[3];
    float* out = (float*)d_out;
    float* ws  = (float*)d_ws;

    void* args[] = {(void*)&x, (void*)&idx, (void*)&w, (void*)&bias,
                    (void*)&out, (void*)&ws};
    hipLaunchCooperativeKernel(reinterpret_cast<void*>(ill_fused),
                               dim3(GRID), dim3(BLOCK), args, 0, stream);
}

// Round 5
// 26.588 us; speedup vs baseline: 8.2631x; 8.2631x over previous
//
#include <hip/hip_runtime.h>

#define SIZE_IN   8192
#define SIZE_OUT  2048
#define CH        16                 // i's per split
#define NSPLIT    (SIZE_IN / CH)     // 512 splits
#define JT        2                  // j tiles per split
#define JTILE     (SIZE_OUT / JT)    // 1024 floats
#define BLOCK     256

typedef float f4 __attribute__((ext_vector_type(4)));  // clang-native for nontemporal

// Kernel 1: block = (i-chunk, j-half). Thread owns one float4 of j.
// Weights are read exactly once -> nontemporal (streaming) loads keep the
// 64 MiB gather from thrashing L2 (ws/x/idx stay cached).
__global__ __launch_bounds__(BLOCK) void ill_partial(
    const float* __restrict__ x,
    const int*   __restrict__ idx,
    const float* __restrict__ w,
    float*       __restrict__ ws)
{
    const int jt  = blockIdx.x & (JT - 1);
    const int ic  = blockIdx.x / JT;
    const int tid = threadIdx.x;
    const int j   = jt * JTILE + tid * 4;
    const int i0  = ic * CH;

    f4 acc = (f4)(0.f);

    #pragma unroll
    for (int k = 0; k < CH; ++k) {
        const int    i  = i0 + k;              // wave-uniform -> scalar loads
        const float  xv = x[i];
        const size_t q  = (size_t)idx[i];
        const f4 wv = __builtin_nontemporal_load(
            reinterpret_cast<const f4*>(
                w + ((q << 13) + (size_t)i) * (size_t)SIZE_OUT + j));
        acc += xv * wv;
    }

    *reinterpret_cast<f4*>(ws + (size_t)ic * SIZE_OUT + j) = acc;
}

// Kernel 2: one block per float4 column (512 blocks -> all CUs busy).
// Thread t sums splits {t, t+256}; shfl tree + LDS finishes the column.
__global__ __launch_bounds__(BLOCK) void ill_reduce(
    const float* __restrict__ ws,
    const float* __restrict__ bias,
    float*       __restrict__ out)
{
    const int j4  = blockIdx.x;                 // 0..511
    const int tid = threadIdx.x;
    const f4* ws4 = reinterpret_cast<const f4*>(ws);

    f4 acc = ws4[(size_t)tid * (SIZE_OUT / 4) + j4]
           + ws4[(size_t)(tid + BLOCK) * (SIZE_OUT / 4) + j4];

    #pragma unroll
    for (int off = 32; off > 0; off >>= 1) {
        acc.x += __shfl_down(acc.x, off, 64);
        acc.y += __shfl_down(acc.y, off, 64);
        acc.z += __shfl_down(acc.z, off, 64);
        acc.w += __shfl_down(acc.w, off, 64);
    }

    __shared__ f4 sred[BLOCK / 64];
    const int lane = tid & 63;
    const int wvid = tid >> 6;
    if (lane == 0) sred[wvid] = acc;
    __syncthreads();

    if (tid == 0) {
        f4 s = sred[0];
        #pragma unroll
        for (int u = 1; u < BLOCK / 64; ++u) s += sred[u];
        const f4 bv = reinterpret_cast<const f4*>(bias)[j4];
        s += bv;
        *reinterpret_cast<f4*>(reinterpret_cast<float*>(out) + j4 * 4) = s;
    }
}

extern "C" void kernel_launch(void* const* d_in, const int* in_sizes, int n_in,
                              void* d_out, int out_size, void* d_ws, size_t ws_size,
                              hipStream_t stream) {
    const float* x    = (const float*)d_in[0];
    const int*   idx  = (const int*)d_in[1];
    const float* w    = (const float*)d_in[2];
    const float* bias = (const float*)d_in[3];
    float* out = (float*)d_out;
    float* ws  = (float*)d_ws;

    ill_partial<<<dim3(NSPLIT * JT), dim3(BLOCK), 0, stream>>>(x, idx, w, ws);
    ill_reduce<<<dim3(SIZE_OUT / 4), dim3(BLOCK), 0, stream>>>(ws, bias, out);
}

// Round 6
// 23.412 us; speedup vs baseline: 9.3839x; 1.1356x over previous
//
#include <hip/hip_runtime.h>

#define SIZE_IN   8192
#define SIZE_OUT  2048
#define CH        16                 // i's per split
#define NSPLIT    (SIZE_IN / CH)     // 512 splits
#define JT        2                  // j tiles per split
#define JTILE     (SIZE_OUT / JT)    // 1024 floats
#define BLOCK     256

typedef float f4 __attribute__((ext_vector_type(4)));

// Kernel 1: block = (i-chunk, j-half). Thread owns one float4 of j.
// Plain cached loads: the 64 MiB gathered weight set is L2/L3-warm across
// graph replays — nontemporal loads regressed 5 µs by bypassing the cache.
__global__ __launch_bounds__(BLOCK) void ill_partial(
    const float* __restrict__ x,
    const int*   __restrict__ idx,
    const float* __restrict__ w,
    float*       __restrict__ ws)
{
    const int jt  = blockIdx.x & (JT - 1);
    const int ic  = blockIdx.x / JT;
    const int tid = threadIdx.x;
    const int j   = jt * JTILE + tid * 4;
    const int i0  = ic * CH;

    f4 acc = (f4)(0.f);

    #pragma unroll
    for (int k = 0; k < CH; ++k) {
        const int    i  = i0 + k;              // wave-uniform -> scalar loads
        const float  xv = x[i];
        const size_t q  = (size_t)idx[i];
        const f4 wv = *reinterpret_cast<const f4*>(
            w + ((q << 13) + (size_t)i) * (size_t)SIZE_OUT + j);
        acc += xv * wv;
    }

    *reinterpret_cast<f4*>(ws + (size_t)ic * SIZE_OUT + j) = acc;
}

// Kernel 2: one block per float4 column (512 blocks -> all CUs busy).
// Thread t sums splits {t, t+256}; shfl tree + LDS finishes the column.
__global__ __launch_bounds__(BLOCK) void ill_reduce(
    const float* __restrict__ ws,
    const float* __restrict__ bias,
    float*       __restrict__ out)
{
    const int j4  = blockIdx.x;                 // 0..511
    const int tid = threadIdx.x;
    const f4* ws4 = reinterpret_cast<const f4*>(ws);

    f4 acc = ws4[(size_t)tid * (SIZE_OUT / 4) + j4]
           + ws4[(size_t)(tid + BLOCK) * (SIZE_OUT / 4) + j4];

    #pragma unroll
    for (int off = 32; off > 0; off >>= 1) {
        acc.x += __shfl_down(acc.x, off, 64);
        acc.y += __shfl_down(acc.y, off, 64);
        acc.z += __shfl_down(acc.z, off, 64);
        acc.w += __shfl_down(acc.w, off, 64);
    }

    __shared__ f4 sred[BLOCK / 64];
    const int lane = tid & 63;
    const int wvid = tid >> 6;
    if (lane == 0) sred[wvid] = acc;
    __syncthreads();

    if (tid == 0) {
        f4 s = sred[0];
        #pragma unroll
        for (int u = 1; u < BLOCK / 64; ++u) s += sred[u];
        s += reinterpret_cast<const f4*>(bias)[j4];
        *reinterpret_cast<f4*>(reinterpret_cast<float*>(out) + j4 * 4) = s;
    }
}

extern "C" void kernel_launch(void* const* d_in, const int* in_sizes, int n_in,
                              void* d_out, int out_size, void* d_ws, size_t ws_size,
                              hipStream_t stream) {
    const float* x    = (const float*)d_in[0];
    const int*   idx  = (const int*)d_in[1];
    const float* w    = (const float*)d_in[2];
    const float* bias = (const float*)d_in[3];
    float* out = (float*)d_out;
    float* ws  = (float*)d_ws;

    ill_partial<<<dim3(NSPLIT * JT), dim3(BLOCK), 0, stream>>>(x, idx, w, ws);
    ill_reduce<<<dim3(SIZE_OUT / 4), dim3(BLOCK), 0, stream>>>(ws, bias, out);
}

// Round 7
// 18.968 us; speedup vs baseline: 11.5827x; 1.2343x over previous
//
#include <hip/hip_runtime.h>

#define SIZE_IN   8192
#define SIZE_OUT  2048
#define CH        32                 // i's per split
#define NSPLIT    (SIZE_IN / CH)     // 256 splits -> ws = 2 MiB
#define JT        2                  // j tiles per split
#define JTILE     (SIZE_OUT / JT)    // 1024 floats
#define BLOCK     256

typedef float f4 __attribute__((ext_vector_type(4)));

// Kernel 1: block = (i-chunk, j-half). Thread owns one float4 of j.
// Plain cached loads (nt regressed 5 us: weight set is cache-warm across
// replays). 512 blocks = 2/CU, 8 waves/CU -> ample outstanding loads.
__global__ __launch_bounds__(BLOCK) void ill_partial(
    const float* __restrict__ x,
    const int*   __restrict__ idx,
    const float* __restrict__ w,
    float*       __restrict__ ws)
{
    const int jt  = blockIdx.x & (JT - 1);
    const int ic  = blockIdx.x / JT;
    const int tid = threadIdx.x;
    const int j   = jt * JTILE + tid * 4;
    const int i0  = ic * CH;

    f4 acc = (f4)(0.f);

    #pragma unroll
    for (int k = 0; k < CH; ++k) {
        const int    i  = i0 + k;              // wave-uniform -> scalar path
        const float  xv = x[i];
        const size_t q  = (size_t)idx[i];
        const f4 wv = *reinterpret_cast<const f4*>(
            w + ((q << 13) + (size_t)i) * (size_t)SIZE_OUT + j);
        acc += xv * wv;
    }

    *reinterpret_cast<f4*>(ws + (size_t)ic * SIZE_OUT + j) = acc;
}

// Kernel 2: one WAVE per f4 column (R2's best-measured shape, now only
// 256 splits). Lane l sums rows {l, l+64, l+128, l+192}; shfl tree; lane 0
// adds bias and writes. Grid = 128 blocks -> 512 waves.
__global__ __launch_bounds__(BLOCK) void ill_reduce(
    const float* __restrict__ ws,
    const float* __restrict__ bias,
    float*       __restrict__ out)
{
    const int lane = threadIdx.x & 63;
    const int j4   = blockIdx.x * (BLOCK / 64) + (threadIdx.x >> 6);
    const f4* ws4  = reinterpret_cast<const f4*>(ws);

    f4 acc = (f4)(0.f);
    #pragma unroll
    for (int r = 0; r < NSPLIT / 64; ++r) {
        acc += ws4[(size_t)(r * 64 + lane) * (SIZE_OUT / 4) + j4];
    }

    #pragma unroll
    for (int off = 32; off > 0; off >>= 1) {
        acc.x += __shfl_down(acc.x, off, 64);
        acc.y += __shfl_down(acc.y, off, 64);
        acc.z += __shfl_down(acc.z, off, 64);
        acc.w += __shfl_down(acc.w, off, 64);
    }

    if (lane == 0) {
        acc += reinterpret_cast<const f4*>(bias)[j4];
        *reinterpret_cast<f4*>(reinterpret_cast<float*>(out) + j4 * 4) = acc;
    }
}

extern "C" void kernel_launch(void* const* d_in, const int* in_sizes, int n_in,
                              void* d_out, int out_size, void* d_ws, size_t ws_size,
                              hipStream_t stream) {
    const float* x    = (const float*)d_in[0];
    const int*   idx  = (const int*)d_in[1];
    const float* w    = (const float*)d_in[2];
    const float* bias = (const float*)d_in[3];
    float* out = (float*)d_out;
    float* ws  = (float*)d_ws;

    ill_partial<<<dim3(NSPLIT * JT), dim3(BLOCK), 0, stream>>>(x, idx, w, ws);
    ill_reduce<<<dim3((SIZE_OUT / 4) / (BLOCK / 64)), dim3(BLOCK), 0, stream>>>(
        ws, bias, out);
}

// Round 8
// 17.738 us; speedup vs baseline: 12.3858x; 1.0693x over previous
//
#include <hip/hip_runtime.h>

#define SIZE_IN   8192
#define SIZE_OUT  2048
#define CH        64                 // i's per split
#define NSPLIT    (SIZE_IN / CH)     // 128 splits -> ws = 1 MiB
#define JT        2                  // j tiles per split
#define JTILE     (SIZE_OUT / JT)    // 1024 floats
#define BLOCK     256

typedef float f4 __attribute__((ext_vector_type(4)));

// Kernel 1: block = (i-chunk, j-half). Thread owns one float4 of j.
// Plain cached loads (nt regressed: weight set is cache-warm across replays).
// Grid = 256 blocks = 1/CU; latency hidden by the 64-deep unrolled load
// stream (measured trend R6->R7: fewer, longer blocks win).
__global__ __launch_bounds__(BLOCK) void ill_partial(
    const float* __restrict__ x,
    const int*   __restrict__ idx,
    const float* __restrict__ w,
    float*       __restrict__ ws)
{
    const int jt  = blockIdx.x & (JT - 1);
    const int ic  = blockIdx.x / JT;
    const int tid = threadIdx.x;
    const int j   = jt * JTILE + tid * 4;
    const int i0  = ic * CH;

    f4 acc = (f4)(0.f);

    #pragma unroll
    for (int k = 0; k < CH; ++k) {
        const int    i  = i0 + k;              // wave-uniform -> scalar path
        const float  xv = x[i];
        const size_t q  = (size_t)idx[i];
        const f4 wv = *reinterpret_cast<const f4*>(
            w + ((q << 13) + (size_t)i) * (size_t)SIZE_OUT + j);
        acc += xv * wv;
    }

    *reinterpret_cast<f4*>(ws + (size_t)ic * SIZE_OUT + j) = acc;
}

// Kernel 2: one WAVE per f4 column. Lane l sums rows {l, l+64}; shfl tree;
// lane 0 adds bias and writes. Grid = 128 blocks (512 waves).
__global__ __launch_bounds__(BLOCK) void ill_reduce(
    const float* __restrict__ ws,
    const float* __restrict__ bias,
    float*       __restrict__ out)
{
    const int lane = threadIdx.x & 63;
    const int j4   = blockIdx.x * (BLOCK / 64) + (threadIdx.x >> 6);
    const f4* ws4  = reinterpret_cast<const f4*>(ws);

    f4 acc = (f4)(0.f);
    #pragma unroll
    for (int r = 0; r < NSPLIT / 64; ++r) {
        acc += ws4[(size_t)(r * 64 + lane) * (SIZE_OUT / 4) + j4];
    }

    #pragma unroll
    for (int off = 32; off > 0; off >>= 1) {
        acc.x += __shfl_down(acc.x, off, 64);
        acc.y += __shfl_down(acc.y, off, 64);
        acc.z += __shfl_down(acc.z, off, 64);
        acc.w += __shfl_down(acc.w, off, 64);
    }

    if (lane == 0) {
        acc += reinterpret_cast<const f4*>(bias)[j4];
        *reinterpret_cast<f4*>(reinterpret_cast<float*>(out) + j4 * 4) = acc;
    }
}

extern "C" void kernel_launch(void* const* d_in, const int* in_sizes, int n_in,
                              void* d_out, int out_size, void* d_ws, size_t ws_size,
                              hipStream_t stream) {
    const float* x    = (const float*)d_in[0];
    const int*   idx  = (const int*)d_in[1];
    const float* w    = (const float*)d_in[2];
    const float* bias = (const float*)d_in[3];
    float* out = (float*)d_out;
    float* ws  = (float*)d_ws;

    ill_partial<<<dim3(NSPLIT * JT), dim3(BLOCK), 0, stream>>>(x, idx, w, ws);
    ill_reduce<<<dim3((SIZE_OUT / 4) / (BLOCK / 64)), dim3(BLOCK), 0, stream>>>(
        ws, bias, out);
}